// Round 7
// baseline (952.091 us; speedup 1.0000x reference)
//
#include <hip/hip_runtime.h>
#include <stdint.h>

// Problem dims (fixed)
#define BB 4
#define LL 4096
#define DM 2048
#define HH 32
#define NN 128
#define MM (BB*LL)        // 16384
#define KK 2048
#define NPAD 384          // 2N+H=288 padded to 3*128
#define NBN_SSM 3         // first 3 bn-tiles of the merged GEMM -> ssm
#define NCH 64            // scan chunks per sequence
#define CT  (LL/NCH)      // 64 steps per chunk

// ---------- helpers ----------
__device__ __forceinline__ unsigned short f2bf(float f) {
    union { float f; uint32_t u; } c; c.f = f;
    uint32_t u = c.u;
    uint32_t r = (u + 0x7FFFu + ((u >> 16) & 1u)) >> 16;
    return (unsigned short)r;
}
__device__ __forceinline__ float bf2f(unsigned short b) {
    union { uint32_t u; float f; } c; c.u = ((uint32_t)b) << 16;
    return c.f;
}

typedef __attribute__((ext_vector_type(4))) float f32x4;
typedef __attribute__((ext_vector_type(8))) __bf16 bf16x8;

typedef __attribute__((address_space(1))) uint32_t u32_g;
typedef __attribute__((address_space(3))) uint32_t u32_l;

__device__ __forceinline__ void async16(const void* g, void* l) {
    __builtin_amdgcn_global_load_lds((const u32_g*)g, (u32_l*)l, 16, 0, 0);
}

// ---------- cast x -> bf16 ----------
__global__ __launch_bounds__(256) void cast_f32_bf16(const float* __restrict__ in,
                                                     unsigned short* __restrict__ out) {
    size_t i = ((size_t)blockIdx.x * 256 + threadIdx.x) * 4;
    float4 v = *(const float4*)(in + i);
    ushort4 o;
    o.x = f2bf(v.x); o.y = f2bf(v.y); o.z = f2bf(v.z); o.w = f2bf(v.w);
    *(ushort4*)(out + i) = o;
}

// ---------- cast + transpose W[K][N] -> WT[Npad][K] (bf16, zero-pad rows) ----------
__global__ __launch_bounds__(256) void cast_transpose(const float* __restrict__ W,
                                                      unsigned short* __restrict__ WT,
                                                      int K, int N) {
    __shared__ float tile[32][33];
    int k0 = blockIdx.x * 32, n0 = blockIdx.y * 32;
    int tx = threadIdx.x, ty = threadIdx.y;   // block (32,8)
    #pragma unroll
    for (int i = ty; i < 32; i += 8) {
        int k = k0 + i, n = n0 + tx;
        tile[i][tx] = (n < N) ? W[(size_t)k * N + n] : 0.f;
    }
    __syncthreads();
    #pragma unroll
    for (int i = ty; i < 32; i += 8) {
        int n = n0 + i, k = k0 + tx;
        WT[(size_t)n * K + k] = f2bf(tile[tx][i]);
    }
}

// ---------- shared GEMM core macros ----------
// Tile 128x128, BK=64, 256 threads (4 waves, 2x2 of 64x64), global_load_lds staging.
// 1-D grid + XCD-aware bijective swizzle (T1); nbx == 128 (=MM/Bb) so the post-
// swizzle decompose is shift/mask. Consecutive post-swizzle ids on one XCD share a
// bn-row -> B-panel (512KB) stays L2-resident.
#define Bb 128
#define BKk 64

#define GEMM_PROLOGUE()                                                        \
    __shared__ unsigned short As[Bb * BKk];                                    \
    __shared__ unsigned short Bs[Bb * BKk];                                    \
    const int tid  = threadIdx.x;                                              \
    const int lane = tid & 63;                                                 \
    const int wid  = tid >> 6;                                                 \
    const int cpx = gridDim.x >> 3;                                            \
    const int swz = (blockIdx.x & 7) * cpx + (blockIdx.x >> 3);                \
    const int bm = (swz & 127) * Bb;                                           \
    const int bn_tile = swz >> 7;                                              \
    const int bn = bn_tile * Bb;                                               \
    const int wm = (wid >> 1) * 64;                                            \
    const int wn = (wid & 1) * 64;                                             \
    f32x4 acc[4][4];                                                           \
    _Pragma("unroll")                                                          \
    for (int i = 0; i < 4; ++i)                                                \
        _Pragma("unroll")                                                      \
        for (int j = 0; j < 4; ++j)                                            \
            acc[i][j] = (f32x4){0.f, 0.f, 0.f, 0.f};                           \
    const int lin_row = (tid * 16) >> 7;                                       \
    const int lin_colb = (tid * 16) & 127;                                     \
    const int wave_base = (tid & ~63) * 16;

#define GEMM_KLOOP(Ap, Bp, K)                                                  \
    for (int k0 = 0; k0 < (K); k0 += BKk) {                                    \
        _Pragma("unroll")                                                      \
        for (int c = 0; c < 4; ++c) {                                          \
            int row = c * 32 + lin_row;                                        \
            const unsigned short* ga = (Ap) + (size_t)(bm + row) * (K) + k0 + (lin_colb >> 1); \
            async16(ga, (char*)As + c * 4096 + wave_base);                     \
        }                                                                      \
        _Pragma("unroll")                                                      \
        for (int c = 0; c < 4; ++c) {                                          \
            int row = c * 32 + lin_row;                                        \
            const unsigned short* gb = (Bp) + (size_t)(bn + row) * (K) + k0 + (lin_colb >> 1); \
            async16(gb, (char*)Bs + c * 4096 + wave_base);                     \
        }                                                                      \
        __syncthreads();                                                       \
        _Pragma("unroll")                                                      \
        for (int kk = 0; kk < 2; ++kk) {                                       \
            bf16x8 af[4], bfv[4];                                              \
            _Pragma("unroll")                                                  \
            for (int mi = 0; mi < 4; ++mi)                                     \
                af[mi] = *(const bf16x8*)&As[(wm + mi * 16 + (lane & 15)) * BKk + kk * 32 + (lane >> 4) * 8]; \
            _Pragma("unroll")                                                  \
            for (int ni = 0; ni < 4; ++ni)                                     \
                bfv[ni] = *(const bf16x8*)&Bs[(wn + ni * 16 + (lane & 15)) * BKk + kk * 32 + (lane >> 4) * 8]; \
            _Pragma("unroll")                                                  \
            for (int mi = 0; mi < 4; ++mi)                                     \
                _Pragma("unroll")                                              \
                for (int ni = 0; ni < 4; ++ni)                                 \
                    acc[mi][ni] = __builtin_amdgcn_mfma_f32_16x16x32_bf16(af[mi], bfv[ni], acc[mi][ni], 0, 0, 0); \
        }                                                                      \
        __syncthreads();                                                       \
    }

// ---------- merged GEMM: [ssm | gate] = xb @ [WxT | WgT]^T ----------
// BT has 2432 rows (384 WxT + 2048 WgT, contiguous in ws). bn-tiles 0..2 -> fp32
// store to ssm (ldc=NPAD); tiles 3..18 -> sigmoid(acc+bg) -> bf16 gate (ldc=DM).
// Branch is block-uniform. Grid 128*19 = 2432 wgs (2432%8==0, swizzle bijective).
__global__ __launch_bounds__(256) void gemm_xw(const unsigned short* __restrict__ A,
                                               const unsigned short* __restrict__ BT,
                                               float* __restrict__ ssm,
                                               unsigned short* __restrict__ gate,
                                               const float* __restrict__ bg) {
    GEMM_PROLOGUE()
    GEMM_KLOOP(A, BT, KK)
    if (bn_tile < NBN_SSM) {
        #pragma unroll
        for (int mi = 0; mi < 4; ++mi)
            #pragma unroll
            for (int ni = 0; ni < 4; ++ni)
                #pragma unroll
                for (int r = 0; r < 4; ++r) {
                    int row = bm + wm + mi * 16 + (lane >> 4) * 4 + r;
                    int col = bn + wn + ni * 16 + (lane & 15);
                    ssm[(size_t)row * NPAD + col] = acc[mi][ni][r];
                }
    } else {
        const int gcol0 = bn - NBN_SSM * Bb;
        #pragma unroll
        for (int mi = 0; mi < 4; ++mi)
            #pragma unroll
            for (int ni = 0; ni < 4; ++ni)
                #pragma unroll
                for (int r = 0; r < 4; ++r) {
                    int row = bm + wm + mi * 16 + (lane >> 4) * 4 + r;
                    int col = gcol0 + wn + ni * 16 + (lane & 15);
                    float v = acc[mi][ni][r] + bg[col];
                    v = 1.f / (1.f + __expf(-v));
                    gate[(size_t)row * DM + col] = f2bf(v);
                }
    }
}

// ---------- final GEMM: out = yfull @ WoT^T (fp32 store) ----------
__global__ __launch_bounds__(256) void gemm_out(const unsigned short* __restrict__ A,
                                                const unsigned short* __restrict__ BT,
                                                float* __restrict__ Cout) {
    GEMM_PROLOGUE()
    GEMM_KLOOP(A, BT, KK)
    #pragma unroll
    for (int mi = 0; mi < 4; ++mi)
        #pragma unroll
        for (int ni = 0; ni < 4; ++ni)
            #pragma unroll
            for (int r = 0; r < 4; ++r) {
                int row = bm + wm + mi * 16 + (lane >> 4) * 4 + r;
                int col = bn + wn + ni * 16 + (lane & 15);
                Cout[(size_t)row * DM + col] = acc[mi][ni][r];
            }
}

// ---------- chunked scan, h-shared ----------
// h_t = a_t*h_{t-1} + b_t (linear, contractive). Pass1: per-(b,chunk) block computes
// (prod a, h_end | h0=0) for ALL 32 heads (B/db staged in LDS once per row — B/C are
// shared across heads, removing the 32x redundant ssm reads). Pass2: sequential
// combine over chunks. Pass3: recompute from true init, fused C-contraction + D-skip
// + gate epilogue (D-skip uses the bf16 x copy; result is bf16-quantized anyway).
// Thread layout pass1/3: tid -> h = tid>>3, tg = tid&7; thread owns states
// n = tg + 8*j, j in [0,16). chunk arrays layout: [(b*HH+h)*NCH + c]*NN + n.

__global__ __launch_bounds__(256) void scan_pass1(const float* __restrict__ ssm,
                                                  const float* __restrict__ Amat,
                                                  float* __restrict__ chunkA,
                                                  float* __restrict__ chunkH) {
    __shared__ float sB[NN];
    __shared__ float sDb[HH];
    const int tid = threadIdx.x;
    const int c = blockIdx.x & (NCH - 1);
    const int b = blockIdx.x >> 6;           // NCH=64
    const int h = tid >> 3, tg = tid & 7;
    float Ar[16], st[16], pr[16];
    #pragma unroll
    for (int j = 0; j < 16; ++j) {
        Ar[j] = Amat[h * NN + tg + 8 * j];
        st[j] = 0.f; pr[j] = 1.f;
    }
    const int t0 = c * CT;
    for (int t = t0; t < t0 + CT; ++t) {
        const float* sp = ssm + ((size_t)b * LL + t) * NPAD;
        if (tid < NN) sB[tid] = sp[tid];
        if (tid < HH) sDb[tid] = sp[256 + tid];
        __syncthreads();
        const float db = sDb[h];
        #pragma unroll
        for (int j = 0; j < 16; ++j) {
            float u = db + sB[tg + 8 * j];
            float d = fmaxf(u, 0.f) + __logf(1.f + __expf(-fabsf(u)));
            float e = __expf(d * Ar[j]);
            st[j] = e * st[j] + d * d;
            pr[j] *= e;
        }
        __syncthreads();
    }
    const size_t o = ((size_t)(b * HH + h) * NCH + c) * NN;
    #pragma unroll
    for (int j = 0; j < 16; ++j) {
        chunkA[o + tg + 8 * j] = pr[j];
        chunkH[o + tg + 8 * j] = st[j];
    }
}

__global__ __launch_bounds__(64) void scan_pass2(const float* __restrict__ chunkA,
                                                 const float* __restrict__ chunkH,
                                                 float* __restrict__ Hinit) {
    const int lane = threadIdx.x;
    const size_t base = (size_t)blockIdx.x * NCH * NN;   // blockIdx = b*HH+h
    float2 H = make_float2(0.f, 0.f);
    for (int c = 0; c < NCH; ++c) {
        size_t o = base + (size_t)c * NN;
        *(float2*)&Hinit[o + 2 * lane] = H;
        float2 a  = *(const float2*)&chunkA[o + 2 * lane];
        float2 hh = *(const float2*)&chunkH[o + 2 * lane];
        H.x = a.x * H.x + hh.x;
        H.y = a.y * H.y + hh.y;
    }
}

__global__ __launch_bounds__(256) void scan_pass3(const float* __restrict__ ssm,
                                                  const unsigned short* __restrict__ xb,
                                                  const unsigned short* __restrict__ gate,
                                                  const float* __restrict__ Amat,
                                                  const float* __restrict__ Dp,
                                                  const float* __restrict__ Hinit,
                                                  unsigned short* __restrict__ yfull) {
    __shared__ float sB[NN];
    __shared__ float sC[NN];
    __shared__ float sDb[HH];
    const int tid = threadIdx.x;
    const int c = blockIdx.x & (NCH - 1);
    const int b = blockIdx.x >> 6;
    const int h = tid >> 3, tg = tid & 7;
    const float dp = Dp[h];
    float Ar[16], st[16];
    const size_t o = ((size_t)(b * HH + h) * NCH + c) * NN;
    #pragma unroll
    for (int j = 0; j < 16; ++j) {
        Ar[j] = Amat[h * NN + tg + 8 * j];
        st[j] = Hinit[o + tg + 8 * j];
    }
    const int t0 = c * CT;
    for (int t = t0; t < t0 + CT; ++t) {
        const size_t row = (size_t)b * LL + t;
        const float* sp = ssm + row * NPAD;
        if (tid < NN) sB[tid] = sp[tid];
        else sC[tid - NN] = sp[tid];         // sp[128..255] = C
        if (tid < HH) sDb[tid] = sp[256 + tid];
        __syncthreads();
        const float db = sDb[h];
        float y = 0.f;
        #pragma unroll
        for (int j = 0; j < 16; ++j) {
            float u = db + sB[tg + 8 * j];
            float d = fmaxf(u, 0.f) + __logf(1.f + __expf(-fabsf(u)));
            st[j] = __expf(d * Ar[j]) * st[j] + d * d;
            y += st[j] * sC[tg + 8 * j];
        }
        y += __shfl_xor(y, 1, 64);
        y += __shfl_xor(y, 2, 64);
        y += __shfl_xor(y, 4, 64);
        // epilogue: this thread covers hd = tg*8 .. tg*8+7. Reads its own xb range,
        // then overwrites it (yfull aliases xb) — read-before-write within thread.
        const size_t xi = row * (size_t)DM + h * 64 + tg * 8;
        ushort4 xv0 = *(const ushort4*)&xb[xi];
        ushort4 xv1 = *(const ushort4*)&xb[xi + 4];
        ushort4 g0 = *(const ushort4*)&gate[xi];
        ushort4 g1 = *(const ushort4*)&gate[xi + 4];
        ushort4 o0, o1;
        o0.x = f2bf((y + bf2f(xv0.x) * dp) * bf2f(g0.x));
        o0.y = f2bf((y + bf2f(xv0.y) * dp) * bf2f(g0.y));
        o0.z = f2bf((y + bf2f(xv0.z) * dp) * bf2f(g0.z));
        o0.w = f2bf((y + bf2f(xv0.w) * dp) * bf2f(g0.w));
        o1.x = f2bf((y + bf2f(xv1.x) * dp) * bf2f(g1.x));
        o1.y = f2bf((y + bf2f(xv1.y) * dp) * bf2f(g1.y));
        o1.z = f2bf((y + bf2f(xv1.z) * dp) * bf2f(g1.z));
        o1.w = f2bf((y + bf2f(xv1.w) * dp) * bf2f(g1.w));
        *(ushort4*)&yfull[xi] = o0;
        *(ushort4*)&yfull[xi + 4] = o1;
        __syncthreads();
    }
}

// ---------- launch ----------
extern "C" void kernel_launch(void* const* d_in, const int* in_sizes, int n_in,
                              void* d_out, int out_size, void* d_ws, size_t ws_size,
                              hipStream_t stream) {
    const float* x  = (const float*)d_in[0];
    const float* Wx = (const float*)d_in[1];
    const float* Wg = (const float*)d_in[2];
    const float* bg = (const float*)d_in[3];
    const float* Wo = (const float*)d_in[4];
    const float* Am = (const float*)d_in[5];
    const float* Dp = (const float*)d_in[6];
    float* out = (float*)d_out;

    char* w = (char*)d_ws;
    unsigned short* xb     = (unsigned short*)(w);                 // 67108864 B (reused as yfull)
    unsigned short* WxT    = (unsigned short*)(w + 67108864);      // 1572864  } contiguous:
    unsigned short* WgT    = (unsigned short*)(w + 68681728);      // 8388608  } 2432-row BT
    unsigned short* WoT    = (unsigned short*)(w + 77070336);      // 8388608
    float*          ssm    = (float*)         (w + 85458944);      // 25165824
    unsigned short* gate   = (unsigned short*)(w + 110624768);     // 67108864
    float*          chunkA = (float*)         (w + 177733632);     // 4194304
    float*          chunkH = (float*)         (w + 181927936);     // 4194304
    float*          Hinit  = (float*)         (w + 186122240);     // 4194304  (total 190316544)
    unsigned short* yfull = xb;  // x (bf16) dead after gemm_xw; pass3 rewrites in place

    // 1. cast x -> bf16
    cast_f32_bf16<<<dim3(MM * KK / (256 * 4)), dim3(256), 0, stream>>>(x, xb);
    // 2. transpose weights to [N][K] bf16 (WxT||WgT form one contiguous 2432-row BT)
    cast_transpose<<<dim3(KK / 32, NPAD / 32), dim3(32, 8), 0, stream>>>(Wx, WxT, KK, 2 * NN + HH);
    cast_transpose<<<dim3(KK / 32, DM / 32), dim3(32, 8), 0, stream>>>(Wg, WgT, KK, DM);
    cast_transpose<<<dim3(KK / 32, DM / 32), dim3(32, 8), 0, stream>>>(Wo, WoT, KK, DM);
    // 3+4 merged: [ssm | gate] = xb @ [WxT|WgT]^T  (128*19 = 2432 wgs)
    gemm_xw<<<dim3(128 * (NBN_SSM + DM / Bb)), dim3(256), 0, stream>>>(xb, WxT, ssm, gate, bg);
    // 5. chunked scan: pass1 (per-chunk prefix, h-shared), pass2 (combine), pass3 (recompute + epilogue)
    scan_pass1<<<dim3(BB * NCH), dim3(256), 0, stream>>>(ssm, Am, chunkA, chunkH);
    scan_pass2<<<dim3(BB * HH), dim3(64), 0, stream>>>(chunkA, chunkH, Hinit);
    scan_pass3<<<dim3(BB * NCH), dim3(256), 0, stream>>>(ssm, xb, gate, Am, Dp, Hinit, yfull);
    // 6. out = yfull @ WoT^T  (128*16 = 2048 wgs)
    gemm_out<<<dim3(128 * (DM / Bb)), dim3(256), 0, stream>>>(yfull, WoT, out);
}

// Round 8
// 948.821 us; speedup vs baseline: 1.0034x; 1.0034x over previous
//
#include <hip/hip_runtime.h>
#include <stdint.h>

// Problem dims (fixed)
#define BB 4
#define LL 4096
#define DM 2048
#define HH 32
#define NN 128
#define MM (BB*LL)        // 16384
#define KK 2048
#define NPAD 384          // 2N+H=288 padded to 3*128
#define NBN_SSM 3         // first 3 bn-tiles of the merged GEMM -> ssm
#define NCH 64            // scan chunks per sequence
#define CT  (LL/NCH)      // 64 steps per chunk

// ---------- helpers ----------
__device__ __forceinline__ unsigned short f2bf(float f) {
    union { float f; uint32_t u; } c; c.f = f;
    uint32_t u = c.u;
    uint32_t r = (u + 0x7FFFu + ((u >> 16) & 1u)) >> 16;
    return (unsigned short)r;
}
__device__ __forceinline__ float bf2f(unsigned short b) {
    union { uint32_t u; float f; } c; c.u = ((uint32_t)b) << 16;
    return c.f;
}

typedef __attribute__((ext_vector_type(4))) float f32x4;
typedef __attribute__((ext_vector_type(8))) __bf16 bf16x8;

typedef __attribute__((address_space(1))) uint32_t u32_g;
typedef __attribute__((address_space(3))) uint32_t u32_l;

__device__ __forceinline__ void async16(const void* g, void* l) {
    __builtin_amdgcn_global_load_lds((const u32_g*)g, (u32_l*)l, 16, 0, 0);
}

// ---------- cast x -> bf16 ----------
__global__ __launch_bounds__(256) void cast_f32_bf16(const float* __restrict__ in,
                                                     unsigned short* __restrict__ out) {
    size_t i = ((size_t)blockIdx.x * 256 + threadIdx.x) * 4;
    float4 v = *(const float4*)(in + i);
    ushort4 o;
    o.x = f2bf(v.x); o.y = f2bf(v.y); o.z = f2bf(v.z); o.w = f2bf(v.w);
    *(ushort4*)(out + i) = o;
}

// ---------- cast + transpose W[K][N] -> WT[Npad][K] (bf16, zero-pad rows) ----------
__global__ __launch_bounds__(256) void cast_transpose(const float* __restrict__ W,
                                                      unsigned short* __restrict__ WT,
                                                      int K, int N) {
    __shared__ float tile[32][33];
    int k0 = blockIdx.x * 32, n0 = blockIdx.y * 32;
    int tx = threadIdx.x, ty = threadIdx.y;   // block (32,8)
    #pragma unroll
    for (int i = ty; i < 32; i += 8) {
        int k = k0 + i, n = n0 + tx;
        tile[i][tx] = (n < N) ? W[(size_t)k * N + n] : 0.f;
    }
    __syncthreads();
    #pragma unroll
    for (int i = ty; i < 32; i += 8) {
        int n = n0 + i, k = k0 + tx;
        WT[(size_t)n * K + k] = f2bf(tile[tx][i]);
    }
}

// ---------- shared GEMM core macros ----------
// Tile 128x128, BK=64, 256 threads (4 waves, 2x2 of 64x64), global_load_lds staging.
// Block->tile mapping (r7): FETCH was A-refetch-bound (622MB = 19 bn-tiles x 32MB A
// streaming through 4MB/XCD L2; dur == bytes/BW). Fix: each XCD owns 2 bm-GROUPS of
// 8 tiles (8x128x2048x2B = 4MB = L2) and iterates ALL bn per group, bm fastest:
//   xcd = wg&7; idx = wg>>3; g = idx/(NTN*8); bn = (idx%(NTN*8))>>3; bmi = idx&7;
//   bm_tile = (xcd*2+g)*8+bmi.
// Bijective: 8 xcd x 2 g x 8 bmi covers 128 bm-tiles; NTN bn covered per group.
// Per-XCD L2 fill: 2x(4MB A-group + 9.5MB B) ~= 27MB -> ~216MB total (was 622MB).
#define Bb 128
#define BKk 64

#define GEMM_PROLOGUE(NTN)                                                     \
    __shared__ unsigned short As[Bb * BKk];                                    \
    __shared__ unsigned short Bs[Bb * BKk];                                    \
    const int tid  = threadIdx.x;                                              \
    const int lane = tid & 63;                                                 \
    const int wid  = tid >> 6;                                                 \
    const int xcd  = blockIdx.x & 7;                                           \
    const int idx  = blockIdx.x >> 3;                                          \
    const int gl   = idx / ((NTN) * 8);                                        \
    const int rem  = idx - gl * ((NTN) * 8);                                   \
    const int bn_tile = rem >> 3;                                              \
    const int bm = (((xcd << 1) + gl) * 8 + (rem & 7)) * Bb;                   \
    const int bn = bn_tile * Bb;                                               \
    const int wm = (wid >> 1) * 64;                                            \
    const int wn = (wid & 1) * 64;                                             \
    f32x4 acc[4][4];                                                           \
    _Pragma("unroll")                                                          \
    for (int i = 0; i < 4; ++i)                                                \
        _Pragma("unroll")                                                      \
        for (int j = 0; j < 4; ++j)                                            \
            acc[i][j] = (f32x4){0.f, 0.f, 0.f, 0.f};                           \
    const int lin_row = (tid * 16) >> 7;                                       \
    const int lin_colb = (tid * 16) & 127;                                     \
    const int wave_base = (tid & ~63) * 16;

#define GEMM_KLOOP(Ap, Bp, K)                                                  \
    for (int k0 = 0; k0 < (K); k0 += BKk) {                                    \
        _Pragma("unroll")                                                      \
        for (int c = 0; c < 4; ++c) {                                          \
            int row = c * 32 + lin_row;                                        \
            const unsigned short* ga = (Ap) + (size_t)(bm + row) * (K) + k0 + (lin_colb >> 1); \
            async16(ga, (char*)As + c * 4096 + wave_base);                     \
        }                                                                      \
        _Pragma("unroll")                                                      \
        for (int c = 0; c < 4; ++c) {                                          \
            int row = c * 32 + lin_row;                                        \
            const unsigned short* gb = (Bp) + (size_t)(bn + row) * (K) + k0 + (lin_colb >> 1); \
            async16(gb, (char*)Bs + c * 4096 + wave_base);                     \
        }                                                                      \
        __syncthreads();                                                       \
        _Pragma("unroll")                                                      \
        for (int kk = 0; kk < 2; ++kk) {                                       \
            bf16x8 af[4], bfv[4];                                              \
            _Pragma("unroll")                                                  \
            for (int mi = 0; mi < 4; ++mi)                                     \
                af[mi] = *(const bf16x8*)&As[(wm + mi * 16 + (lane & 15)) * BKk + kk * 32 + (lane >> 4) * 8]; \
            _Pragma("unroll")                                                  \
            for (int ni = 0; ni < 4; ++ni)                                     \
                bfv[ni] = *(const bf16x8*)&Bs[(wn + ni * 16 + (lane & 15)) * BKk + kk * 32 + (lane >> 4) * 8]; \
            _Pragma("unroll")                                                  \
            for (int mi = 0; mi < 4; ++mi)                                     \
                _Pragma("unroll")                                              \
                for (int ni = 0; ni < 4; ++ni)                                 \
                    acc[mi][ni] = __builtin_amdgcn_mfma_f32_16x16x32_bf16(af[mi], bfv[ni], acc[mi][ni], 0, 0, 0); \
        }                                                                      \
        __syncthreads();                                                       \
    }

// ---------- merged GEMM: [ssm | gate] = xb @ [WxT | WgT]^T ----------
// BT has 2432 rows (384 WxT + 2048 WgT, contiguous in ws). bn-tiles 0..2 -> fp32
// store to ssm (ldc=NPAD); tiles 3..18 -> sigmoid(acc+bg) -> bf16 gate (ldc=DM).
// Branch is block-uniform. Grid 128*19 = 2432 wgs.
__global__ __launch_bounds__(256) void gemm_xw(const unsigned short* __restrict__ A,
                                               const unsigned short* __restrict__ BT,
                                               float* __restrict__ ssm,
                                               unsigned short* __restrict__ gate,
                                               const float* __restrict__ bg) {
    GEMM_PROLOGUE(19)
    GEMM_KLOOP(A, BT, KK)
    if (bn_tile < NBN_SSM) {
        #pragma unroll
        for (int mi = 0; mi < 4; ++mi)
            #pragma unroll
            for (int ni = 0; ni < 4; ++ni)
                #pragma unroll
                for (int r = 0; r < 4; ++r) {
                    int row = bm + wm + mi * 16 + (lane >> 4) * 4 + r;
                    int col = bn + wn + ni * 16 + (lane & 15);
                    ssm[(size_t)row * NPAD + col] = acc[mi][ni][r];
                }
    } else {
        const int gcol0 = bn - NBN_SSM * Bb;
        #pragma unroll
        for (int mi = 0; mi < 4; ++mi)
            #pragma unroll
            for (int ni = 0; ni < 4; ++ni)
                #pragma unroll
                for (int r = 0; r < 4; ++r) {
                    int row = bm + wm + mi * 16 + (lane >> 4) * 4 + r;
                    int col = gcol0 + wn + ni * 16 + (lane & 15);
                    float v = acc[mi][ni][r] + bg[col];
                    v = 1.f / (1.f + __expf(-v));
                    gate[(size_t)row * DM + col] = f2bf(v);
                }
    }
}

// ---------- final GEMM: out = yfull @ WoT^T (fp32 store) ----------
__global__ __launch_bounds__(256) void gemm_out(const unsigned short* __restrict__ A,
                                                const unsigned short* __restrict__ BT,
                                                float* __restrict__ Cout) {
    GEMM_PROLOGUE(16)
    GEMM_KLOOP(A, BT, KK)
    #pragma unroll
    for (int mi = 0; mi < 4; ++mi)
        #pragma unroll
        for (int ni = 0; ni < 4; ++ni)
            #pragma unroll
            for (int r = 0; r < 4; ++r) {
                int row = bm + wm + mi * 16 + (lane >> 4) * 4 + r;
                int col = bn + wn + ni * 16 + (lane & 15);
                Cout[(size_t)row * DM + col] = acc[mi][ni][r];
            }
}

// ---------- chunked scan, h-shared ----------
// h_t = a_t*h_{t-1} + b_t (linear, contractive). Pass1: per-(b,chunk) block computes
// (prod a, h_end | h0=0) for ALL 32 heads (B/db staged in LDS once per row — B/C are
// shared across heads, removing the 32x redundant ssm reads). Pass2: sequential
// combine over chunks. Pass3: recompute from true init, fused C-contraction + D-skip
// + gate epilogue (D-skip uses the bf16 x copy; result is bf16-quantized anyway).
// Thread layout pass1/3: tid -> h = tid>>3, tg = tid&7; thread owns states
// n = tg + 8*j, j in [0,16). chunk arrays layout: [(b*HH+h)*NCH + c]*NN + n.

__global__ __launch_bounds__(256) void scan_pass1(const float* __restrict__ ssm,
                                                  const float* __restrict__ Amat,
                                                  float* __restrict__ chunkA,
                                                  float* __restrict__ chunkH) {
    __shared__ float sB[NN];
    __shared__ float sDb[HH];
    const int tid = threadIdx.x;
    const int c = blockIdx.x & (NCH - 1);
    const int b = blockIdx.x >> 6;           // NCH=64
    const int h = tid >> 3, tg = tid & 7;
    float Ar[16], st[16], pr[16];
    #pragma unroll
    for (int j = 0; j < 16; ++j) {
        Ar[j] = Amat[h * NN + tg + 8 * j];
        st[j] = 0.f; pr[j] = 1.f;
    }
    const int t0 = c * CT;
    for (int t = t0; t < t0 + CT; ++t) {
        const float* sp = ssm + ((size_t)b * LL + t) * NPAD;
        if (tid < NN) sB[tid] = sp[tid];
        if (tid < HH) sDb[tid] = sp[256 + tid];
        __syncthreads();
        const float db = sDb[h];
        #pragma unroll
        for (int j = 0; j < 16; ++j) {
            float u = db + sB[tg + 8 * j];
            float d = fmaxf(u, 0.f) + __logf(1.f + __expf(-fabsf(u)));
            float e = __expf(d * Ar[j]);
            st[j] = e * st[j] + d * d;
            pr[j] *= e;
        }
        __syncthreads();
    }
    const size_t o = ((size_t)(b * HH + h) * NCH + c) * NN;
    #pragma unroll
    for (int j = 0; j < 16; ++j) {
        chunkA[o + tg + 8 * j] = pr[j];
        chunkH[o + tg + 8 * j] = st[j];
    }
}

__global__ __launch_bounds__(64) void scan_pass2(const float* __restrict__ chunkA,
                                                 const float* __restrict__ chunkH,
                                                 float* __restrict__ Hinit) {
    const int lane = threadIdx.x;
    const size_t base = (size_t)blockIdx.x * NCH * NN;   // blockIdx = b*HH+h
    float2 H = make_float2(0.f, 0.f);
    for (int c = 0; c < NCH; ++c) {
        size_t o = base + (size_t)c * NN;
        *(float2*)&Hinit[o + 2 * lane] = H;
        float2 a  = *(const float2*)&chunkA[o + 2 * lane];
        float2 hh = *(const float2*)&chunkH[o + 2 * lane];
        H.x = a.x * H.x + hh.x;
        H.y = a.y * H.y + hh.y;
    }
}

__global__ __launch_bounds__(256) void scan_pass3(const float* __restrict__ ssm,
                                                  const unsigned short* __restrict__ xb,
                                                  const unsigned short* __restrict__ gate,
                                                  const float* __restrict__ Amat,
                                                  const float* __restrict__ Dp,
                                                  const float* __restrict__ Hinit,
                                                  unsigned short* __restrict__ yfull) {
    __shared__ float sB[NN];
    __shared__ float sC[NN];
    __shared__ float sDb[HH];
    const int tid = threadIdx.x;
    const int c = blockIdx.x & (NCH - 1);
    const int b = blockIdx.x >> 6;
    const int h = tid >> 3, tg = tid & 7;
    const float dp = Dp[h];
    float Ar[16], st[16];
    const size_t o = ((size_t)(b * HH + h) * NCH + c) * NN;
    #pragma unroll
    for (int j = 0; j < 16; ++j) {
        Ar[j] = Amat[h * NN + tg + 8 * j];
        st[j] = Hinit[o + tg + 8 * j];
    }
    const int t0 = c * CT;
    for (int t = t0; t < t0 + CT; ++t) {
        const size_t row = (size_t)b * LL + t;
        const float* sp = ssm + row * NPAD;
        if (tid < NN) sB[tid] = sp[tid];
        else sC[tid - NN] = sp[tid];         // sp[128..255] = C
        if (tid < HH) sDb[tid] = sp[256 + tid];
        __syncthreads();
        const float db = sDb[h];
        float y = 0.f;
        #pragma unroll
        for (int j = 0; j < 16; ++j) {
            float u = db + sB[tg + 8 * j];
            float d = fmaxf(u, 0.f) + __logf(1.f + __expf(-fabsf(u)));
            st[j] = __expf(d * Ar[j]) * st[j] + d * d;
            y += st[j] * sC[tg + 8 * j];
        }
        y += __shfl_xor(y, 1, 64);
        y += __shfl_xor(y, 2, 64);
        y += __shfl_xor(y, 4, 64);
        // epilogue: this thread covers hd = tg*8 .. tg*8+7. Reads its own xb range,
        // then overwrites it (yfull aliases xb) — read-before-write within thread.
        const size_t xi = row * (size_t)DM + h * 64 + tg * 8;
        ushort4 xv0 = *(const ushort4*)&xb[xi];
        ushort4 xv1 = *(const ushort4*)&xb[xi + 4];
        ushort4 g0 = *(const ushort4*)&gate[xi];
        ushort4 g1 = *(const ushort4*)&gate[xi + 4];
        ushort4 o0, o1;
        o0.x = f2bf((y + bf2f(xv0.x) * dp) * bf2f(g0.x));
        o0.y = f2bf((y + bf2f(xv0.y) * dp) * bf2f(g0.y));
        o0.z = f2bf((y + bf2f(xv0.z) * dp) * bf2f(g0.z));
        o0.w = f2bf((y + bf2f(xv0.w) * dp) * bf2f(g0.w));
        o1.x = f2bf((y + bf2f(xv1.x) * dp) * bf2f(g1.x));
        o1.y = f2bf((y + bf2f(xv1.y) * dp) * bf2f(g1.y));
        o1.z = f2bf((y + bf2f(xv1.z) * dp) * bf2f(g1.z));
        o1.w = f2bf((y + bf2f(xv1.w) * dp) * bf2f(g1.w));
        *(ushort4*)&yfull[xi] = o0;
        *(ushort4*)&yfull[xi + 4] = o1;
        __syncthreads();
    }
}

// ---------- launch ----------
extern "C" void kernel_launch(void* const* d_in, const int* in_sizes, int n_in,
                              void* d_out, int out_size, void* d_ws, size_t ws_size,
                              hipStream_t stream) {
    const float* x  = (const float*)d_in[0];
    const float* Wx = (const float*)d_in[1];
    const float* Wg = (const float*)d_in[2];
    const float* bg = (const float*)d_in[3];
    const float* Wo = (const float*)d_in[4];
    const float* Am = (const float*)d_in[5];
    const float* Dp = (const float*)d_in[6];
    float* out = (float*)d_out;

    char* w = (char*)d_ws;
    unsigned short* xb     = (unsigned short*)(w);                 // 67108864 B (reused as yfull)
    unsigned short* WxT    = (unsigned short*)(w + 67108864);      // 1572864  } contiguous:
    unsigned short* WgT    = (unsigned short*)(w + 68681728);      // 8388608  } 2432-row BT
    unsigned short* WoT    = (unsigned short*)(w + 77070336);      // 8388608
    float*          ssm    = (float*)         (w + 85458944);      // 25165824
    unsigned short* gate   = (unsigned short*)(w + 110624768);     // 67108864
    float*          chunkA = (float*)         (w + 177733632);     // 4194304
    float*          chunkH = (float*)         (w + 181927936);     // 4194304
    float*          Hinit  = (float*)         (w + 186122240);     // 4194304  (total 190316544)
    unsigned short* yfull = xb;  // x (bf16) dead after gemm_xw; pass3 rewrites in place

    // 1. cast x -> bf16
    cast_f32_bf16<<<dim3(MM * KK / (256 * 4)), dim3(256), 0, stream>>>(x, xb);
    // 2. transpose weights to [N][K] bf16 (WxT||WgT form one contiguous 2432-row BT)
    cast_transpose<<<dim3(KK / 32, NPAD / 32), dim3(32, 8), 0, stream>>>(Wx, WxT, KK, 2 * NN + HH);
    cast_transpose<<<dim3(KK / 32, DM / 32), dim3(32, 8), 0, stream>>>(Wg, WgT, KK, DM);
    cast_transpose<<<dim3(KK / 32, DM / 32), dim3(32, 8), 0, stream>>>(Wo, WoT, KK, DM);
    // 3+4 merged: [ssm | gate] = xb @ [WxT|WgT]^T  (128*19 = 2432 wgs)
    gemm_xw<<<dim3(128 * (NBN_SSM + DM / Bb)), dim3(256), 0, stream>>>(xb, WxT, ssm, gate, bg);
    // 5. chunked scan: pass1 (per-chunk prefix, h-shared), pass2 (combine), pass3 (recompute + epilogue)
    scan_pass1<<<dim3(BB * NCH), dim3(256), 0, stream>>>(ssm, Am, chunkA, chunkH);
    scan_pass2<<<dim3(BB * HH), dim3(64), 0, stream>>>(chunkA, chunkH, Hinit);
    scan_pass3<<<dim3(BB * NCH), dim3(256), 0, stream>>>(ssm, xb, gate, Am, Dp, Hinit, yfull);
    // 6. out = yfull @ WoT^T  (128*16 = 2048 wgs)
    gemm_out<<<dim3(128 * (DM / Bb)), dim3(256), 0, stream>>>(yfull, WoT, out);
}